// Round 7
// baseline (163.292 us; speedup 1.0000x reference)
//
#include <hip/hip_runtime.h>

// Problem constants (fixed by setup_inputs: 64 graphs x 32 nodes)
constexpr int N_NODES = 2048;
constexpr int G       = 64;
constexpr int D       = 512;
constexpr int H       = 8;
constexpr int HD      = 64;
constexpr int E       = 16;
constexpr int M_EDGES = 16384;
constexpr int NWG     = 256;

typedef __attribute__((ext_vector_type(8))) _Float16 f16x8;
typedef __attribute__((ext_vector_type(4))) float f32x4;

// ---------------------------------------------------------------------------
__global__ __launch_bounds__(64) void init_cnt_kernel(int* cnt)
{
    if (threadIdx.x < 2) cnt[threadIdx.x] = 0;
}

// Device-scope grid barrier: all NWG workgroups co-resident (1/CU guaranteed:
// 42KB LDS, 256 thr). Counters zeroed each replay by init_cnt_kernel.
__device__ __forceinline__ void grid_barrier(int* cnt)
{
    __syncthreads();
    if (threadIdx.x == 0) {
        __threadfence();   // release: make my global writes visible device-wide
        __hip_atomic_fetch_add(cnt, 1, __ATOMIC_ACQ_REL, __HIP_MEMORY_SCOPE_AGENT);
        while (__hip_atomic_load(cnt, __ATOMIC_ACQUIRE, __HIP_MEMORY_SCOPE_AGENT) < NWG)
            __builtin_amdgcn_s_sleep(2);
        __threadfence();   // acquire: don't read stale lines
    }
    __syncthreads();
}

__device__ __forceinline__ f16x8 ldg8(const _Float16* p) { return *(const f16x8*)p; }

// ---------------------------------------------------------------------------
// Mega-kernel: P0 prep -> barrier -> P1 QKV+attn -> barrier -> P2 out-GEMM
// ---------------------------------------------------------------------------
__global__ __launch_bounds__(256, 1) void mega_kernel(
    const float* __restrict__ nodes,
    const float* __restrict__ Wq, const float* __restrict__ Wk,
    const float* __restrict__ Wv, const float* __restrict__ Wo,
    const float* __restrict__ bq, const float* __restrict__ bk,
    const float* __restrict__ bv, const float* __restrict__ bo,
    const float* __restrict__ edges, const float* __restrict__ We,
    const float* __restrict__ be,
    const int* __restrict__ snd, const int* __restrict__ rcv,
    _Float16* __restrict__ nA16, _Float16* __restrict__ wT16,
    _Float16* __restrict__ AO16, float* __restrict__ biasM,
    int* __restrict__ cnt, float* __restrict__ out)
{
    const int w = blockIdx.x;
    const int t = threadIdx.x;

    __shared__ int win[1024];                 // P0 role A
    __shared__ float WesS[E][H];
    __shared__ float besS[H];
    __shared__ float wtile[32][33];           // P0 role C
    __shared__ _Float16 QKVs[3][32][132];     // P1: Q,K,V slices (25.3 KB)
    __shared__ float Pl[2][32][33];           // P1: softmax probs

    // ================= Phase 0: prep =================
    if (w < 64) {
        // ---- per-graph edge winner (exact .set: last index wins) + bias ----
        const int g = w;
        if (t < E * H) WesS[t / H][t % H] = We[t];
        if (t < H) besS[t] = be[t];
        for (int idx = t; idx < 1024; idx += 256) win[idx] = -1;
        __syncthreads();
        for (int it = 0; it < M_EDGES / 256; ++it) {
            int m = it * 256 + t;
            int s = snd[m], r = rcv[m];
            if ((s >> 5) == g && (r >> 5) == g)
                atomicMax(&win[((r & 31) << 5) | (s & 31)], m);
        }
        __syncthreads();
        for (int idx = t; idx < 1024; idx += 256) {
            int m = win[idx];
            float ob[H];
            if (m >= 0) {
                float ef[E];
#pragma unroll
                for (int e = 0; e < E; ++e) ef[e] = edges[m * E + e];
#pragma unroll
                for (int hh = 0; hh < H; ++hh) {
                    float v = besS[hh];
#pragma unroll
                    for (int e = 0; e < E; ++e) v += ef[e] * WesS[e][hh];
                    ob[hh] = v;
                }
            } else {
#pragma unroll
                for (int hh = 0; hh < H; ++hh) ob[hh] = 0.f;
            }
#pragma unroll
            for (int hh = 0; hh < H; ++hh)
                biasM[(size_t)((g * H + hh) << 10) + idx] = ob[hh];
        }
    } else if (w < 128) {
        // ---- cast nodes fp32 -> fp16: 64 WGs x 2048 groups of 8 ----
        for (int j = 0; j < 8; ++j) {
            int i = (w - 64) * 2048 + j * 256 + t;
            float4 v0 = ((const float4*)nodes)[2 * i];
            float4 v1 = ((const float4*)nodes)[2 * i + 1];
            float f[8] = { v0.x, v0.y, v0.z, v0.w, v1.x, v1.y, v1.z, v1.w };
            union { _Float16 h[8]; int4 v; } p;
#pragma unroll
            for (int e = 0; e < 8; ++e) p.h[e] = (_Float16)f[e];
            ((int4*)nA16)[i] = p.v;
        }
    } else {
        // ---- transpose + cast weights: 128 WGs x 8 tiles (32x32) ----
        for (int j = 0; j < 8; ++j) {
            int task = (w - 128) * 8 + j;     // 0..1023
            int z   = task >> 8;
            int rem = task & 255;
            int k0  = (rem >> 4) * 32, n0 = (rem & 15) * 32;
            const float* W = (z == 0) ? Wq : (z == 1) ? Wk : (z == 2) ? Wv : Wo;
            {
                int kr = t >> 3, nc4 = (t & 7) * 4;
                float4 v = *(const float4*)(W + (size_t)(k0 + kr) * D + n0 + nc4);
                wtile[nc4 + 0][kr] = v.x;
                wtile[nc4 + 1][kr] = v.y;
                wtile[nc4 + 2][kr] = v.z;
                wtile[nc4 + 3][kr] = v.w;
            }
            __syncthreads();
            {
                int nl = t >> 3, kq = (t & 7) * 4;
                union { _Float16 h[4]; uint2 v; } hi;
#pragma unroll
                for (int jj = 0; jj < 4; ++jj)
                    hi.h[jj] = (_Float16)wtile[nl][kq + jj];
                size_t base = (size_t)z * D * D + (size_t)(n0 + nl) * D + k0 + kq;
                *(uint2*)(wT16 + base) = hi.v;
            }
            __syncthreads();
        }
    }

    grid_barrier(&cnt[0]);

    // ================= Phase 1: QKV (fragment-direct MFMA) + attention =====
    {
        const int g    = w >> 2;       // graph
        const int qq   = w & 3;        // col-quad: cols 128*qq.., heads 2qq,2qq+1
        const int lane = t & 63;
        const int wv   = t >> 6;       // wave 0..3 -> col sub-slice 32*wv

        // A-frag base: row = 32g + mf*16 + (lane&15), k = k0 + ks*32 + (lane>>4)*8
        const _Float16* Ap = nA16 + (size_t)(32 * g + (lane & 15)) * D + (lane >> 4) * 8;
        // B-frag base: n = 128qq + 32wv + nf*16 + (lane&15)
        const _Float16* Bp = wT16 + (size_t)(128 * qq + 32 * wv + (lane & 15)) * D + (lane >> 4) * 8;

        f32x4 acc[3][2][2] = {};
        for (int k0 = 0; k0 < D; k0 += 64) {
            f16x8 fa[2][2];
#pragma unroll
            for (int mf = 0; mf < 2; ++mf)
#pragma unroll
                for (int ks = 0; ks < 2; ++ks)
                    fa[mf][ks] = ldg8(Ap + (size_t)mf * 16 * D + k0 + ks * 32);
#pragma unroll
            for (int z = 0; z < 3; ++z) {
                const _Float16* Bz = Bp + (size_t)z * D * D;
                f16x8 fb[2][2];
#pragma unroll
                for (int nf = 0; nf < 2; ++nf)
#pragma unroll
                    for (int ks = 0; ks < 2; ++ks)
                        fb[nf][ks] = ldg8(Bz + (size_t)nf * 16 * D + k0 + ks * 32);
#pragma unroll
                for (int mf = 0; mf < 2; ++mf)
#pragma unroll
                    for (int nf = 0; nf < 2; ++nf)
#pragma unroll
                        for (int ks = 0; ks < 2; ++ks)
                            acc[z][mf][nf] = __builtin_amdgcn_mfma_f32_16x16x32_f16(
                                fa[mf][ks], fb[nf][ks], acc[z][mf][nf], 0, 0, 0);
            }
        }

        // epilogue: +bias, cast fp16, into LDS (C/D: col=lane&15, row=(lane>>4)*4+r)
#pragma unroll
        for (int z = 0; z < 3; ++z) {
            const float* bz = (z == 0) ? bq : (z == 1) ? bk : bv;
#pragma unroll
            for (int nf = 0; nf < 2; ++nf) {
                int colL = 32 * wv + nf * 16 + (lane & 15);
                float bvv = bz[128 * qq + colL];
#pragma unroll
                for (int mf = 0; mf < 2; ++mf)
#pragma unroll
                    for (int r = 0; r < 4; ++r) {
                        int rowL = mf * 16 + (lane >> 4) * 4 + r;
                        QKVs[z][rowL][colL] = (_Float16)(acc[z][mf][nf][r] + bvv);
                    }
            }
        }
        __syncthreads();

        // ---- attention for heads 2qq, 2qq+1 (local cols hh*64..hh*64+63) ----
        const int i  = t >> 3;          // query row 0..31
        const int j4 = (t & 7) * 4;     // this thread's 4 key cols
#pragma unroll
        for (int hh = 0; hh < 2; ++hh) {
            const int head = 2 * qq + hh;
            float s0 = 0.f, s1 = 0.f, s2 = 0.f, s3 = 0.f;
            for (int d = 0; d < HD; ++d) {
                float qv = (float)QKVs[0][i][hh * 64 + d];
                s0 += qv * (float)QKVs[1][j4 + 0][hh * 64 + d];
                s1 += qv * (float)QKVs[1][j4 + 1][hh * 64 + d];
                s2 += qv * (float)QKVs[1][j4 + 2][hh * 64 + d];
                s3 += qv * (float)QKVs[1][j4 + 3][hh * 64 + d];
            }
            const float* bm = &biasM[(size_t)((g * H + head) << 10) + (i << 5)];
            s0 = s0 * 0.125f + bm[j4 + 0];
            s1 = s1 * 0.125f + bm[j4 + 1];
            s2 = s2 * 0.125f + bm[j4 + 2];
            s3 = s3 * 0.125f + bm[j4 + 3];
            float mx = fmaxf(fmaxf(s0, s1), fmaxf(s2, s3));
#pragma unroll
            for (int o = 4; o > 0; o >>= 1) mx = fmaxf(mx, __shfl_xor(mx, o));
            float p0 = __expf(s0 - mx), p1 = __expf(s1 - mx);
            float p2 = __expf(s2 - mx), p3 = __expf(s3 - mx);
            float sum = p0 + p1 + p2 + p3;
#pragma unroll
            for (int o = 4; o > 0; o >>= 1) sum += __shfl_xor(sum, o);
            float inv = 1.0f / sum;
            Pl[hh][i][j4 + 0] = p0 * inv;
            Pl[hh][i][j4 + 1] = p1 * inv;
            Pl[hh][i][j4 + 2] = p2 * inv;
            Pl[hh][i][j4 + 3] = p3 * inv;
        }
        __syncthreads();

        // ---- PV + AO16 store (8 d-values per thread per head) ----
        const int dq = (t & 7) * 8;
#pragma unroll
        for (int hh = 0; hh < 2; ++hh) {
            float o[8] = {};
            for (int kk = 0; kk < 32; ++kk) {
                float pv = Pl[hh][i][kk];
#pragma unroll
                for (int dd = 0; dd < 8; ++dd)
                    o[dd] += pv * (float)QKVs[2][kk][hh * 64 + dq + dd];
            }
            union { _Float16 h[8]; int4 v; } pk;
#pragma unroll
            for (int dd = 0; dd < 8; ++dd) pk.h[dd] = (_Float16)o[dd];
            *(int4*)(AO16 + (size_t)(32 * g + i) * D + 128 * qq + hh * 64 + dq) = pk.v;
        }
    }

    grid_barrier(&cnt[1]);

    // ================= Phase 2: out = AO16 @ Wo^T + bo =================
    {
        const int bm   = w >> 3;       // 0..31 (row tile of 64)
        const int bn   = w & 7;        // 0..7  (col tile of 64)
        const int lane = t & 63;
        const int wv   = t >> 6;
        const int vm   = wv >> 1, vn = wv & 1;

        const _Float16* Ap = AO16 + (size_t)(64 * bm + 32 * vm + (lane & 15)) * D + (lane >> 4) * 8;
        const _Float16* Bp = wT16 + (size_t)3 * D * D
                           + (size_t)(64 * bn + 32 * vn + (lane & 15)) * D + (lane >> 4) * 8;

        f32x4 acc[2][2] = {};
        for (int k0 = 0; k0 < D; k0 += 64) {
            f16x8 fa[2][2], fb[2][2];
#pragma unroll
            for (int mf = 0; mf < 2; ++mf)
#pragma unroll
                for (int ks = 0; ks < 2; ++ks)
                    fa[mf][ks] = ldg8(Ap + (size_t)mf * 16 * D + k0 + ks * 32);
#pragma unroll
            for (int nf = 0; nf < 2; ++nf)
#pragma unroll
                for (int ks = 0; ks < 2; ++ks)
                    fb[nf][ks] = ldg8(Bp + (size_t)nf * 16 * D + k0 + ks * 32);
#pragma unroll
            for (int mf = 0; mf < 2; ++mf)
#pragma unroll
                for (int nf = 0; nf < 2; ++nf)
#pragma unroll
                    for (int ks = 0; ks < 2; ++ks)
                        acc[mf][nf] = __builtin_amdgcn_mfma_f32_16x16x32_f16(
                            fa[mf][ks], fb[nf][ks], acc[mf][nf], 0, 0, 0);
        }
#pragma unroll
        for (int mf = 0; mf < 2; ++mf)
#pragma unroll
            for (int nf = 0; nf < 2; ++nf) {
                int col = 64 * bn + 32 * vn + nf * 16 + (lane & 15);
                float bvv = bo[col];
#pragma unroll
                for (int r = 0; r < 4; ++r) {
                    int row = 64 * bm + 32 * vm + mf * 16 + (lane >> 4) * 4 + r;
                    out[(size_t)row * D + col] = acc[mf][nf][r] + bvv;
                }
            }
    }
}

// ---------------------------------------------------------------------------
extern "C" void kernel_launch(void* const* d_in, const int* in_sizes, int n_in,
                              void* d_out, int out_size, void* d_ws, size_t ws_size,
                              hipStream_t stream)
{
    const float* nodes = (const float*)d_in[0];
    const float* edges = (const float*)d_in[1];
    const float* Wq    = (const float*)d_in[2];
    const float* bq    = (const float*)d_in[3];
    const float* Wk    = (const float*)d_in[4];
    const float* bk    = (const float*)d_in[5];
    const float* Wv    = (const float*)d_in[6];
    const float* bv    = (const float*)d_in[7];
    const float* Wo    = (const float*)d_in[8];
    const float* bo    = (const float*)d_in[9];
    const float* We    = (const float*)d_in[10];
    const float* be    = (const float*)d_in[11];
    const int* senders   = (const int*)d_in[13];
    const int* receivers = (const int*)d_in[14];

    // workspace layout
    char* ws = (char*)d_ws;
    float*    biasM = (float*)ws;                                // 2 MB
    _Float16* nA16  = (_Float16*)(biasM + (size_t)G * H * 1024); // 2 MB
    _Float16* wT16  = nA16 + (size_t)N_NODES * D;                // 2 MB (4x512x512)
    _Float16* AO16  = wT16 + (size_t)4 * D * D;                  // 2 MB
    int*      cnt   = (int*)(AO16 + (size_t)N_NODES * D);        // 2 ints

    init_cnt_kernel<<<1, 64, 0, stream>>>(cnt);
    mega_kernel<<<NWG, 256, 0, stream>>>(
        nodes, Wq, Wk, Wv, Wo, bq, bk, bv, bo,
        edges, We, be, senders, receivers,
        nA16, wT16, AO16, biasM, cnt, (float*)d_out);
}

// Round 8
// 56.183 us; speedup vs baseline: 2.9064x; 2.9064x over previous
//
#include <hip/hip_runtime.h>

// Problem constants (fixed by setup_inputs: 64 graphs x 32 nodes)
constexpr int N_NODES = 2048;
constexpr int G       = 64;
constexpr int D       = 512;
constexpr int H       = 8;
constexpr int HD      = 64;
constexpr int E       = 16;
constexpr int M_EDGES = 16384;

typedef __attribute__((ext_vector_type(8))) _Float16 f16x8;
typedef __attribute__((ext_vector_type(4))) float f32x4;

__device__ __forceinline__ void load_lds16(const void* g, void* l) {
    __builtin_amdgcn_global_load_lds(
        (const __attribute__((address_space(1))) unsigned int*)g,
        (__attribute__((address_space(3))) unsigned int*)l, 16, 0, 0);
}

// ---------------------------------------------------------------------------
// PREP kernel: blocks [0,512) cast nodes fp32->fp16; [512,1536) transpose+cast
// the 4 weight matrices (WT[z][n][k] = W_z[k][n]).
// ---------------------------------------------------------------------------
__global__ __launch_bounds__(256) void prep_kernel(
    const float* __restrict__ nodes,
    const float* __restrict__ Wq, const float* __restrict__ Wk,
    const float* __restrict__ Wv, const float* __restrict__ Wo,
    _Float16* __restrict__ nA16, _Float16* __restrict__ wT16)
{
    const int bid = blockIdx.x;
    const int t   = threadIdx.x;

    if (bid < 512) {
        int i = bid * 256 + t;                 // 8 floats each
        float4 v0 = ((const float4*)nodes)[2 * i];
        float4 v1 = ((const float4*)nodes)[2 * i + 1];
        float f[8] = { v0.x, v0.y, v0.z, v0.w, v1.x, v1.y, v1.z, v1.w };
        union { _Float16 h[8]; int4 v; } p;
#pragma unroll
        for (int e = 0; e < 8; ++e) p.h[e] = (_Float16)f[e];
        ((int4*)nA16)[i] = p.v;
        return;
    }

    {
        int idx = bid - 512;                   // 0..1023
        int z   = idx >> 8;
        int rem = idx & 255;
        int k0  = (rem >> 4) * 32, n0 = (rem & 15) * 32;
        const float* W = (z == 0) ? Wq : (z == 1) ? Wk : (z == 2) ? Wv : Wo;
        __shared__ float tile[32][33];
        {
            int kr = t >> 3, nc4 = (t & 7) * 4;
            float4 v = *(const float4*)(W + (size_t)(k0 + kr) * D + n0 + nc4);
            tile[nc4 + 0][kr] = v.x;
            tile[nc4 + 1][kr] = v.y;
            tile[nc4 + 2][kr] = v.z;
            tile[nc4 + 3][kr] = v.w;
        }
        __syncthreads();
        {
            int nl = t >> 3, kq = (t & 7) * 4;
            union { _Float16 h[4]; uint2 v; } hi;
#pragma unroll
            for (int j = 0; j < 4; ++j)
                hi.h[j] = (_Float16)tile[nl][kq + j];
            size_t base = (size_t)z * D * D + (size_t)(n0 + nl) * D + k0 + kq;
            *(uint2*)(wT16 + base) = hi.v;
        }
    }
}

// ---------------------------------------------------------------------------
// fp16 MFMA GEMM (QKV): C16 = fp16(A@B' + bias). Tile 64x64, BK=64, 4 waves.
// Same validated structure as R6; epilogue stores fp16.
// ---------------------------------------------------------------------------
struct GemmArgs {
    const _Float16 *A, *BT;
    const float* bias[3];
    _Float16* C;
};

__global__ __launch_bounds__(256) void gemm_qkv_kernel(GemmArgs a)
{
    const int z = blockIdx.z;
    const _Float16* A = a.A;
    const _Float16* B = a.BT + (size_t)z * D * D;
    const float* bias = a.bias[z];
    _Float16* C = a.C + (size_t)z * (size_t)N_NODES * D;

    __shared__ __align__(16) char lds[2][2][8192];   // [buf][A,B]

    const int t    = threadIdx.x;
    const int lane = t & 63;
    const int w    = t >> 6;
    const int wm   = w >> 1, wn = w & 1;
    const int row0 = blockIdx.y * 64;
    const int col0 = blockIdx.x * 64;

    const int prow0 = t >> 3;
    const int lslot = (t & 7) ^ (prow0 & 7);

    auto stage = [&](int buf, int k0) {
        size_t a0 = (size_t)(row0 + prow0) * 1024 + k0 * 2 + lslot * 16;
        size_t a1 = a0 + 32 * 1024;
        size_t b0 = (size_t)(col0 + prow0) * 1024 + k0 * 2 + lslot * 16;
        size_t b1 = b0 + 32 * 1024;
        load_lds16((const char*)A + a0, &lds[buf][0][t * 16]);
        load_lds16((const char*)A + a1, &lds[buf][0][4096 + t * 16]);
        load_lds16((const char*)B + b0, &lds[buf][1][t * 16]);
        load_lds16((const char*)B + b1, &lds[buf][1][4096 + t * 16]);
    };

    f32x4 acc[2][2] = {};

    stage(0, 0);
    __syncthreads();

    int cur = 0;
    for (int step = 0; step < 8; ++step) {
        if (step < 7) stage(cur ^ 1, (step + 1) * 64);

        f16x8 fa[2][2], fb[2][2];
#pragma unroll
        for (int mf = 0; mf < 2; ++mf) {
            int row = wm * 32 + mf * 16 + (lane & 15);
#pragma unroll
            for (int ks = 0; ks < 2; ++ks) {
                int ps = ((ks * 4 + (lane >> 4)) ^ (row & 7)) << 4;
                fa[mf][ks] = *(const f16x8*)&lds[cur][0][row * 128 + ps];
            }
        }
#pragma unroll
        for (int nf = 0; nf < 2; ++nf) {
            int row = wn * 32 + nf * 16 + (lane & 15);
#pragma unroll
            for (int ks = 0; ks < 2; ++ks) {
                int ps = ((ks * 4 + (lane >> 4)) ^ (row & 7)) << 4;
                fb[nf][ks] = *(const f16x8*)&lds[cur][1][row * 128 + ps];
            }
        }
#pragma unroll
        for (int mf = 0; mf < 2; ++mf)
#pragma unroll
            for (int nf = 0; nf < 2; ++nf)
#pragma unroll
                for (int ks = 0; ks < 2; ++ks)
                    acc[mf][nf] = __builtin_amdgcn_mfma_f32_16x16x32_f16(
                        fa[mf][ks], fb[nf][ks], acc[mf][nf], 0, 0, 0);

        __syncthreads();
        cur ^= 1;
    }

#pragma unroll
    for (int mf = 0; mf < 2; ++mf)
#pragma unroll
        for (int nf = 0; nf < 2; ++nf) {
            int col = col0 + wn * 32 + nf * 16 + (lane & 15);
            float bv = bias[col];
#pragma unroll
            for (int r = 0; r < 4; ++r) {
                int row = row0 + wm * 32 + mf * 16 + (lane >> 4) * 4 + r;
                C[(size_t)row * D + col] = (_Float16)(acc[mf][nf][r] + bv);
            }
        }
}

// ---------------------------------------------------------------------------
// Fused attention + out-GEMM. WG = graph (64 WGs x 1024 thr = 16 waves,
// 4 waves/SIMD). LDS ~138 KB, manually aliased (AO reuses dead Q).
// Phases: stage QKV fp16 + edge-winner scan -> scores (MFMA) -> softmax+bias
// (vector) -> PV (vector) -> out-GEMM (MFMA, A from LDS, B=Wo^T from L2).
// ---------------------------------------------------------------------------
__global__ __launch_bounds__(1024) void attn_out_kernel(
    const _Float16* __restrict__ QKV16,   // [3][N][D] fp16
    const _Float16* __restrict__ WoT,     // [512][512] fp16 (wT16 slot 3)
    const float* __restrict__ bo,
    const float* __restrict__ edges, const float* __restrict__ We,
    const float* __restrict__ be,
    const int* __restrict__ snd, const int* __restrict__ rcv,
    float* __restrict__ out)
{
    const int g = blockIdx.x;
    const int t = threadIdx.x;

    // LDS layout (bytes): rows padded to 520 halfs = 1040 B (65 granules ->
    // 16-row b128 column reads are 2-way = free)
    __shared__ __align__(16) char sm[141376];
    _Float16* Qs  = (_Float16*)(sm);            // [32][520]; later AO
    _Float16* Ks  = (_Float16*)(sm + 33280);    // [32][520]
    _Float16* Vs  = (_Float16*)(sm + 66560);    // [32][520]
    int*      win = (int*)(sm + 99840);         // [1024]
    float*    S   = (float*)(sm + 103936);      // [8][32][36]
    float*    Wes = (float*)(sm + 140800);      // [E][H]
    float*    bes = (float*)(sm + 141312);      // [H]

    // ---- init ----
    if (t < E * H) Wes[t] = We[t];
    if (t < H) bes[t] = be[t];
    win[t] = -1;
    __syncthreads();

    // ---- stage Q/K/V + edge-winner scan (independent LDS regions) ----
    {
        const int srow = t & 31;
        const int slg  = (t >> 5) * 2;
        const size_t gb = (size_t)(32 * g + srow) * D + slg * 8;
#pragma unroll
        for (int z = 0; z < 3; ++z) {
            _Float16* dst = (z == 0) ? Qs : (z == 1) ? Ks : Vs;
            f16x8 v0 = *(const f16x8*)(QKV16 + (size_t)z * N_NODES * D + gb);
            f16x8 v1 = *(const f16x8*)(QKV16 + (size_t)z * N_NODES * D + gb + 8);
            *(f16x8*)((char*)dst + srow * 1040 + slg * 16)      = v0;
            *(f16x8*)((char*)dst + srow * 1040 + slg * 16 + 16) = v1;
        }
        for (int it = 0; it < M_EDGES / 1024; ++it) {
            int m = it * 1024 + t;
            int s = snd[m], r = rcv[m];
            if ((s >> 5) == g && (r >> 5) == g)
                atomicMax(&win[((r & 31) << 5) | (s & 31)], m);
        }
    }
    __syncthreads();

    // ---- scores via MFMA: wave w -> head w>>1, col-half w&1 ----
    {
        const int lane = t & 63;
        const int w    = t >> 6;
        const int h    = w >> 1;
        const int nh   = w & 1;
        f32x4 acc[2] = {};
        const int kb = 64 * h + (lane >> 4) * 8;
#pragma unroll
        for (int ks = 0; ks < 2; ++ks) {
            int kcol = kb + ks * 32;
            f16x8 fb = *(const f16x8*)((char*)Ks + (nh * 16 + (lane & 15)) * 1040 + kcol * 2);
#pragma unroll
            for (int mf = 0; mf < 2; ++mf) {
                f16x8 fa = *(const f16x8*)((char*)Qs + (mf * 16 + (lane & 15)) * 1040 + kcol * 2);
                acc[mf] = __builtin_amdgcn_mfma_f32_16x16x32_f16(fa, fb, acc[mf], 0, 0, 0);
            }
        }
#pragma unroll
        for (int mf = 0; mf < 2; ++mf)
#pragma unroll
            for (int r = 0; r < 4; ++r)
                S[(h * 32 + mf * 16 + (lane >> 4) * 4 + r) * 36 + nh * 16 + (lane & 15)]
                    = acc[mf][r];
    }
    __syncthreads();

    // ---- softmax + inline edge bias (thread = cell (i,j), loop heads) ----
    {
        const int i = t >> 5, j = t & 31;
        int m = win[(i << 5) | j];
        float ef[E];
        if (m >= 0) {
#pragma unroll
            for (int e = 0; e < E; ++e) ef[e] = edges[m * E + e];
        }
        for (int h = 0; h < H; ++h) {
            float s = S[(h * 32 + i) * 36 + j] * 0.125f;
            if (m >= 0) {
                float v = bes[h];
#pragma unroll
                for (int e = 0; e < E; ++e) v += ef[e] * Wes[e * H + h];
                s += v;
            }
            float mx = s;
#pragma unroll
            for (int o = 16; o > 0; o >>= 1) mx = fmaxf(mx, __shfl_xor(mx, o));
            float p = __expf(s - mx);
            float sum = p;
#pragma unroll
            for (int o = 16; o > 0; o >>= 1) sum += __shfl_xor(sum, o);
            S[(h * 32 + i) * 36 + j] = p / sum;
        }
    }
    __syncthreads();

    // ---- PV (vector), AO fp16 written over dead Q ----
    {
        const int i  = t >> 5;
        const int c0 = t & 31;
#pragma unroll
        for (int cc2 = 0; cc2 < 2; ++cc2) {
            int cc = c0 + cc2 * 32;            // d-chunk 0..63 (8 halfs each)
            int h  = cc >> 3;
            const float* Ph = &S[(h * 32 + i) * 36];
            float o[8] = {};
            for (int kk = 0; kk < 32; ++kk) {
                float p = Ph[kk];
                f16x8 v = *(const f16x8*)((char*)Vs + kk * 1040 + cc * 16);
#pragma unroll
                for (int dd = 0; dd < 8; ++dd) o[dd] += p * (float)v[dd];
            }
            union { _Float16 h8[8]; f16x8 v; } pk;
#pragma unroll
            for (int dd = 0; dd < 8; ++dd) pk.h8[dd] = (_Float16)o[dd];
            *(f16x8*)((char*)Qs + i * 1040 + cc * 16) = pk.v;   // AO
        }
    }
    __syncthreads();

    // ---- out-GEMM: wave w -> cols [32w, 32w+32), A = AO (LDS), B = WoT ----
    {
        const int lane = t & 63;
        const int w    = t >> 6;
        f32x4 acc[2][2] = {};
        const _Float16* Bp = WoT + (size_t)(32 * w + (lane & 15)) * D + (lane >> 4) * 8;
        const char*     Ap = (const char*)Qs + (lane & 15) * 1040 + ((lane >> 4) * 8) * 2;
        for (int k0 = 0; k0 < D; k0 += 64) {
            f16x8 fa[2][2], fb[2][2];
#pragma unroll
            for (int mf = 0; mf < 2; ++mf)
#pragma unroll
                for (int ks = 0; ks < 2; ++ks)
                    fa[mf][ks] = *(const f16x8*)(Ap + mf * 16 * 1040 + (k0 + ks * 32) * 2);
#pragma unroll
            for (int nf = 0; nf < 2; ++nf)
#pragma unroll
                for (int ks = 0; ks < 2; ++ks)
                    fb[nf][ks] = *(const f16x8*)(Bp + (size_t)nf * 16 * D + k0 + ks * 32);
#pragma unroll
            for (int mf = 0; mf < 2; ++mf)
#pragma unroll
                for (int nf = 0; nf < 2; ++nf)
#pragma unroll
                    for (int ks = 0; ks < 2; ++ks)
                        acc[mf][nf] = __builtin_amdgcn_mfma_f32_16x16x32_f16(
                            fa[mf][ks], fb[nf][ks], acc[mf][nf], 0, 0, 0);
        }
#pragma unroll
        for (int nf = 0; nf < 2; ++nf) {
            int col = 32 * w + nf * 16 + (lane & 15);
            float bvv = bo[col];
#pragma unroll
            for (int mf = 0; mf < 2; ++mf)
#pragma unroll
                for (int r = 0; r < 4; ++r) {
                    int row = 32 * g + mf * 16 + (lane >> 4) * 4 + r;
                    out[(size_t)row * D + col] = acc[mf][nf][r] + bvv;
                }
        }
    }
}

// ---------------------------------------------------------------------------
extern "C" void kernel_launch(void* const* d_in, const int* in_sizes, int n_in,
                              void* d_out, int out_size, void* d_ws, size_t ws_size,
                              hipStream_t stream)
{
    const float* nodes = (const float*)d_in[0];
    const float* edges = (const float*)d_in[1];
    const float* Wq    = (const float*)d_in[2];
    const float* bq    = (const float*)d_in[3];
    const float* Wk    = (const float*)d_in[4];
    const float* bk    = (const float*)d_in[5];
    const float* Wv    = (const float*)d_in[6];
    const float* bv    = (const float*)d_in[7];
    const float* Wo    = (const float*)d_in[8];
    const float* bo    = (const float*)d_in[9];
    const float* We    = (const float*)d_in[10];
    const float* be    = (const float*)d_in[11];
    const int* senders   = (const int*)d_in[13];
    const int* receivers = (const int*)d_in[14];

    // workspace layout
    char* ws = (char*)d_ws;
    _Float16* nA16  = (_Float16*)ws;                       // 2 MB
    _Float16* wT16  = nA16 + (size_t)N_NODES * D;          // 2 MB (4x512x512)
    _Float16* QKV16 = wT16 + (size_t)4 * D * D;            // 6 MB (3x2048x512)

    // 1) prep: node cast + weight transpose/cast
    prep_kernel<<<1536, 256, 0, stream>>>(nodes, Wq, Wk, Wv, Wo, nA16, wT16);

    // 2) QKV GEMM -> fp16
    GemmArgs qkv;
    qkv.A = nA16;
    qkv.BT = wT16;
    qkv.bias[0] = bq; qkv.bias[1] = bk; qkv.bias[2] = bv;
    qkv.C = QKV16;
    gemm_qkv_kernel<<<dim3(D / 64, N_NODES / 64, 3), 256, 0, stream>>>(qkv);

    // 3) fused attention + out-GEMM
    attn_out_kernel<<<G, 1024, 0, stream>>>(
        QKV16, wT16 + (size_t)3 * D * D, bo, edges, We, be,
        senders, receivers, (float*)d_out);
}

// Round 9
// 48.938 us; speedup vs baseline: 3.3367x; 1.1480x over previous
//
#include <hip/hip_runtime.h>

// Problem constants (fixed by setup_inputs: 64 graphs x 32 nodes)
constexpr int N_NODES = 2048;
constexpr int G       = 64;
constexpr int D       = 512;
constexpr int H       = 8;
constexpr int HD      = 64;
constexpr int E       = 16;
constexpr int M_EDGES = 16384;

typedef __attribute__((ext_vector_type(8))) _Float16 f16x8;
typedef __attribute__((ext_vector_type(4))) float f32x4;

__device__ __forceinline__ void load_lds16(const void* g, void* l) {
    __builtin_amdgcn_global_load_lds(
        (const __attribute__((address_space(1))) unsigned int*)g,
        (__attribute__((address_space(3))) unsigned int*)l, 16, 0, 0);
}

// ---------------------------------------------------------------------------
// PREP kernel (one dispatch, 3 roles by blockIdx.x):
//   blocks [0,64):     per-graph edge winner (LDS atomicMax, exact .set
//                      last-index-wins) + precomputed bias matrix [G][H][32][32]
//   blocks [64,576):   cast nodes fp32 -> fp16            (512 blocks)
//   blocks [576,1600): transpose+cast weights -> fp16     (1024 blocks)
// ---------------------------------------------------------------------------
__global__ __launch_bounds__(256) void prep_kernel(
    const float* __restrict__ nodes,
    const float* __restrict__ Wq, const float* __restrict__ Wk,
    const float* __restrict__ Wv, const float* __restrict__ Wo,
    const float* __restrict__ edges, const float* __restrict__ We,
    const float* __restrict__ be,
    const int* __restrict__ snd, const int* __restrict__ rcv,
    _Float16* __restrict__ nA16, _Float16* __restrict__ wT16,
    float* __restrict__ biasM)
{
    const int bid = blockIdx.x;
    const int t   = threadIdx.x;

    if (bid < G) {
        const int g = bid;
        __shared__ int win[1024];
        __shared__ float Wes[E][H];
        __shared__ float bes[H];
        if (t < E * H) Wes[t / H][t % H] = We[t];
        if (t < H) bes[t] = be[t];
        for (int idx = t; idx < 1024; idx += 256) win[idx] = -1;
        __syncthreads();
        for (int it = 0; it < M_EDGES / 256; ++it) {
            int m = it * 256 + t;
            int s = snd[m], r = rcv[m];
            if ((s >> 5) == g && (r >> 5) == g)
                atomicMax(&win[((r & 31) << 5) | (s & 31)], m);
        }
        __syncthreads();
        for (int idx = t; idx < 1024; idx += 256) {
            int m = win[idx];
            float ob[H];
            if (m >= 0) {
                float ef[E];
#pragma unroll
                for (int e = 0; e < E; ++e) ef[e] = edges[m * E + e];
#pragma unroll
                for (int hh = 0; hh < H; ++hh) {
                    float v = bes[hh];
#pragma unroll
                    for (int e = 0; e < E; ++e) v += ef[e] * Wes[e][hh];
                    ob[hh] = v;
                }
            } else {
#pragma unroll
                for (int hh = 0; hh < H; ++hh) ob[hh] = 0.f;
            }
#pragma unroll
            for (int hh = 0; hh < H; ++hh)
                biasM[(size_t)((g * H + hh) << 10) + idx] = ob[hh];
        }
        return;
    }

    if (bid < G + 512) {
        int i = (bid - G) * 256 + t;           // 8 floats each
        float4 v0 = ((const float4*)nodes)[2 * i];
        float4 v1 = ((const float4*)nodes)[2 * i + 1];
        float f[8] = { v0.x, v0.y, v0.z, v0.w, v1.x, v1.y, v1.z, v1.w };
        union { _Float16 h[8]; int4 v; } p;
#pragma unroll
        for (int e = 0; e < 8; ++e) p.h[e] = (_Float16)f[e];
        ((int4*)nA16)[i] = p.v;
        return;
    }

    {
        int idx = bid - (G + 512);             // 0..1023
        int z   = idx >> 8;
        int rem = idx & 255;
        int k0  = (rem >> 4) * 32, n0 = (rem & 15) * 32;
        const float* W = (z == 0) ? Wq : (z == 1) ? Wk : (z == 2) ? Wv : Wo;
        __shared__ float tile[32][33];
        {
            int kr = t >> 3, nc4 = (t & 7) * 4;
            float4 v = *(const float4*)(W + (size_t)(k0 + kr) * D + n0 + nc4);
            tile[nc4 + 0][kr] = v.x;
            tile[nc4 + 1][kr] = v.y;
            tile[nc4 + 2][kr] = v.z;
            tile[nc4 + 3][kr] = v.w;
        }
        __syncthreads();
        {
            int nl = t >> 3, kq = (t & 7) * 4;
            union { _Float16 h[4]; uint2 v; } hi;
#pragma unroll
            for (int j = 0; j < 4; ++j)
                hi.h[j] = (_Float16)tile[nl][kq + j];
            size_t base = (size_t)z * D * D + (size_t)(n0 + nl) * D + k0 + kq;
            *(uint2*)(wT16 + base) = hi.v;
        }
    }
}

// ---------------------------------------------------------------------------
// fp16 MFMA GEMM, triple-buffered with counted vmcnt (T4-lite):
//   C = A@B' + bias   (B transposed [N][K]); tile 64x64, BK=64, 4 waves.
// Per step t: s_waitcnt vmcnt(4) [tile t's 4 loads done; tile t+1's stay in
// flight] -> s_barrier -> stage tile t+2 -> ds_read tile t -> MFMA.
// LDS 48 KB (3 x 16 KB) -> 3 blocks/CU. Swizzle: 16B-slot ^= row&7.
// ---------------------------------------------------------------------------
template <typename CT>
__device__ __forceinline__ void gemm_body(
    const _Float16* __restrict__ A, const _Float16* __restrict__ B,
    const float* __restrict__ bias, CT* __restrict__ C,
    int row0, int col0)
{
    __shared__ __align__(16) char lds[3][2][8192];   // [buf][A,B]

    const int t    = threadIdx.x;
    const int lane = t & 63;
    const int w    = t >> 6;
    const int wm   = w >> 1, wn = w & 1;

    const int prow0 = t >> 3;
    const int lslot = (t & 7) ^ (prow0 & 7);

    auto stage = [&](int buf, int k0) {
        size_t a0 = (size_t)(row0 + prow0) * 1024 + k0 * 2 + lslot * 16;
        size_t a1 = a0 + 32 * 1024;
        size_t b0 = (size_t)(col0 + prow0) * 1024 + k0 * 2 + lslot * 16;
        size_t b1 = b0 + 32 * 1024;
        load_lds16((const char*)A + a0, &lds[buf][0][t * 16]);
        load_lds16((const char*)A + a1, &lds[buf][0][4096 + t * 16]);
        load_lds16((const char*)B + b0, &lds[buf][1][t * 16]);
        load_lds16((const char*)B + b1, &lds[buf][1][4096 + t * 16]);
    };

    f32x4 acc[2][2] = {};

    stage(0, 0);
    stage(1, 64);

#pragma unroll
    for (int step = 0; step < 8; ++step) {
        // wait: this step's tile staged (all 4 of its loads are my oldest 4)
        if (step < 7) asm volatile("s_waitcnt vmcnt(4)" ::: "memory");
        else          asm volatile("s_waitcnt vmcnt(0)" ::: "memory");
        __builtin_amdgcn_s_barrier();      // all waves' tile-t loads now visible
        if (step < 6) stage((step + 2) % 3, (step + 2) * 64);

        const int cur = step % 3;
        f16x8 fa[2][2], fb[2][2];
#pragma unroll
        for (int mf = 0; mf < 2; ++mf) {
            int row = wm * 32 + mf * 16 + (lane & 15);
#pragma unroll
            for (int ks = 0; ks < 2; ++ks) {
                int ps = ((ks * 4 + (lane >> 4)) ^ (row & 7)) << 4;
                fa[mf][ks] = *(const f16x8*)&lds[cur][0][row * 128 + ps];
            }
        }
#pragma unroll
        for (int nf = 0; nf < 2; ++nf) {
            int row = wn * 32 + nf * 16 + (lane & 15);
#pragma unroll
            for (int ks = 0; ks < 2; ++ks) {
                int ps = ((ks * 4 + (lane >> 4)) ^ (row & 7)) << 4;
                fb[nf][ks] = *(const f16x8*)&lds[cur][1][row * 128 + ps];
            }
        }
#pragma unroll
        for (int mf = 0; mf < 2; ++mf)
#pragma unroll
            for (int nf = 0; nf < 2; ++nf)
#pragma unroll
                for (int ks = 0; ks < 2; ++ks)
                    acc[mf][nf] = __builtin_amdgcn_mfma_f32_16x16x32_f16(
                        fa[mf][ks], fb[nf][ks], acc[mf][nf], 0, 0, 0);
    }

    // epilogue: C/D layout col=lane&15, row=(lane>>4)*4+reg
#pragma unroll
    for (int mf = 0; mf < 2; ++mf)
#pragma unroll
        for (int nf = 0; nf < 2; ++nf) {
            int col = col0 + wn * 32 + nf * 16 + (lane & 15);
            float bv = bias[col];
#pragma unroll
            for (int r = 0; r < 4; ++r) {
                int row = row0 + wm * 32 + mf * 16 + (lane >> 4) * 4 + r;
                C[(size_t)row * D + col] = (CT)(acc[mf][nf][r] + bv);
            }
        }
}

struct GemmArgs {
    const _Float16 *A, *BT;
    const float* bias[3];
    void* C;
};

__global__ __launch_bounds__(256) void gemm_qkv_kernel(GemmArgs a)
{
    const int z = blockIdx.z;
    gemm_body<_Float16>(a.A, a.BT + (size_t)z * D * D, a.bias[z],
                        (_Float16*)a.C + (size_t)z * (size_t)N_NODES * D,
                        blockIdx.y * 64, blockIdx.x * 64);
}

__global__ __launch_bounds__(256) void gemm_out_kernel(GemmArgs a)
{
    gemm_body<float>(a.A, a.BT, a.bias[0], (float*)a.C,
                     blockIdx.y * 64, blockIdx.x * 64);
}

// ---------------------------------------------------------------------------
// Per-(graph, head) block-diagonal attention; bias precomputed by prep;
// fp16 QKV in (converted to fp32 LDS tiles), fp16 AO out.
// ---------------------------------------------------------------------------
__global__ __launch_bounds__(1024) void attn_kernel(
    const _Float16* __restrict__ QKV16, const float* __restrict__ biasM,
    _Float16* __restrict__ AO16)
{
    const int g = blockIdx.x;
    const int h = blockIdx.y;
    __shared__ float Qs[32][64];
    __shared__ float Ks[32][65];
    __shared__ float Vs[32][65];
    __shared__ float P[32][33];

    const int tid = threadIdx.x;
    const _Float16* Q16 = QKV16;
    const _Float16* K16 = QKV16 + (size_t)N_NODES * D;
    const _Float16* V16 = QKV16 + (size_t)2 * N_NODES * D;
    for (int idx = tid; idx < 32 * 64; idx += 1024) {
        int n = idx >> 6, d = idx & 63;
        size_t ga = (size_t)(g * 32 + n) * D + h * HD + d;
        Qs[n][d] = (float)Q16[ga];
        Ks[n][d] = (float)K16[ga];
        Vs[n][d] = (float)V16[ga];
    }
    __syncthreads();

    const int i = tid >> 5;        // query row (receiver)
    const int j = tid & 31;        // key col (sender)
    float s = 0.f;
#pragma unroll
    for (int d = 0; d < 64; ++d) s += Qs[i][d] * Ks[j][d];
    s = s * 0.125f + biasM[(size_t)((g * H + h) << 10) + (i << 5) + j];

    float mx = s;
#pragma unroll
    for (int o = 16; o > 0; o >>= 1) mx = fmaxf(mx, __shfl_xor(mx, o));
    float p = __expf(s - mx);
    float sum = p;
#pragma unroll
    for (int o = 16; o > 0; o >>= 1) sum += __shfl_xor(sum, o);
    p /= sum;
    P[i][j] = p;
    __syncthreads();

    float o0 = 0.f, o1 = 0.f;
#pragma unroll
    for (int kk = 0; kk < 32; ++kk) {
        float pv = P[i][kk];
        o0 += pv * Vs[kk][j];
        o1 += pv * Vs[kk][j + 32];
    }
    size_t oa = (size_t)(g * 32 + i) * D + h * HD;
    AO16[oa + j]      = (_Float16)o0;
    AO16[oa + j + 32] = (_Float16)o1;
}

// ---------------------------------------------------------------------------
extern "C" void kernel_launch(void* const* d_in, const int* in_sizes, int n_in,
                              void* d_out, int out_size, void* d_ws, size_t ws_size,
                              hipStream_t stream)
{
    const float* nodes = (const float*)d_in[0];
    const float* edges = (const float*)d_in[1];
    const float* Wq    = (const float*)d_in[2];
    const float* bq    = (const float*)d_in[3];
    const float* Wk    = (const float*)d_in[4];
    const float* bk    = (const float*)d_in[5];
    const float* Wv    = (const float*)d_in[6];
    const float* bv    = (const float*)d_in[7];
    const float* Wo    = (const float*)d_in[8];
    const float* bo    = (const float*)d_in[9];
    const float* We    = (const float*)d_in[10];
    const float* be    = (const float*)d_in[11];
    const int* senders   = (const int*)d_in[13];
    const int* receivers = (const int*)d_in[14];

    // workspace layout
    char* ws = (char*)d_ws;
    float*    biasM = (float*)ws;                                // 2 MB
    _Float16* nA16  = (_Float16*)(biasM + (size_t)G * H * 1024); // 2 MB
    _Float16* wT16  = nA16 + (size_t)N_NODES * D;                // 2 MB (4x512x512)
    _Float16* QKV16 = wT16 + (size_t)4 * D * D;                  // 6 MB (3x2048x512)
    _Float16* AO16  = QKV16 + (size_t)3 * N_NODES * D;           // 2 MB

    // 1) prep: bias matrix + node cast + weight transpose/cast
    prep_kernel<<<G + 512 + 1024, 256, 0, stream>>>(
        nodes, Wq, Wk, Wv, Wo, edges, We, be, senders, receivers,
        nA16, wT16, biasM);

    // 2) QKV GEMM -> fp16
    GemmArgs qkv;
    qkv.A = nA16;
    qkv.BT = wT16;
    qkv.bias[0] = bq; qkv.bias[1] = bk; qkv.bias[2] = bv;
    qkv.C = QKV16;
    gemm_qkv_kernel<<<dim3(D / 64, N_NODES / 64, 3), 256, 0, stream>>>(qkv);

    // 3) attention
    attn_kernel<<<dim3(G, H), 1024, 0, stream>>>(QKV16, biasM, AO16);

    // 4) output GEMM (Wo at slot 3)
    GemmArgs og;
    og.A = AO16;
    og.BT = wT16 + (size_t)3 * D * D;
    og.bias[0] = bo; og.bias[1] = bo; og.bias[2] = bo;
    og.C = d_out;
    gemm_out_kernel<<<dim3(D / 64, N_NODES / 64), 256, 0, stream>>>(og);
}

// Round 10
// 38.205 us; speedup vs baseline: 4.2741x; 1.2809x over previous
//
#include <hip/hip_runtime.h>

// Problem constants (fixed by setup_inputs: 64 graphs x 32 nodes)
constexpr int N_NODES = 2048;
constexpr int G       = 64;
constexpr int D       = 512;
constexpr int H       = 8;
constexpr int HD      = 64;
constexpr int E       = 16;
constexpr int M_EDGES = 16384;

typedef __attribute__((ext_vector_type(8))) _Float16 f16x8;
typedef __attribute__((ext_vector_type(4))) float f32x4;

__device__ __forceinline__ void load_lds16(const void* g, void* l) {
    __builtin_amdgcn_global_load_lds(
        (const __attribute__((address_space(1))) unsigned int*)g,
        (__attribute__((address_space(3))) unsigned int*)l, 16, 0, 0);
}

// ---------------------------------------------------------------------------
// PREP kernel: blocks [0,512) cast nodes fp32->fp16; [512,1536) transpose+cast
// the 4 weight matrices (WT[z][n][k] = W_z[k][n]).   (R8-proven version)
// ---------------------------------------------------------------------------
__global__ __launch_bounds__(256) void prep_kernel(
    const float* __restrict__ nodes,
    const float* __restrict__ Wq, const float* __restrict__ Wk,
    const float* __restrict__ Wv, const float* __restrict__ Wo,
    _Float16* __restrict__ nA16, _Float16* __restrict__ wT16)
{
    const int bid = blockIdx.x;
    const int t   = threadIdx.x;

    if (bid < 512) {
        int i = bid * 256 + t;                 // 8 floats each
        float4 v0 = ((const float4*)nodes)[2 * i];
        float4 v1 = ((const float4*)nodes)[2 * i + 1];
        float f[8] = { v0.x, v0.y, v0.z, v0.w, v1.x, v1.y, v1.z, v1.w };
        union { _Float16 h[8]; int4 v; } p;
#pragma unroll
        for (int e = 0; e < 8; ++e) p.h[e] = (_Float16)f[e];
        ((int4*)nA16)[i] = p.v;
        return;
    }

    {
        int idx = bid - 512;                   // 0..1023
        int z   = idx >> 8;
        int rem = idx & 255;
        int k0  = (rem >> 4) * 32, n0 = (rem & 15) * 32;
        const float* W = (z == 0) ? Wq : (z == 1) ? Wk : (z == 2) ? Wv : Wo;
        __shared__ float tile[32][33];
        {
            int kr = t >> 3, nc4 = (t & 7) * 4;
            float4 v = *(const float4*)(W + (size_t)(k0 + kr) * D + n0 + nc4);
            tile[nc4 + 0][kr] = v.x;
            tile[nc4 + 1][kr] = v.y;
            tile[nc4 + 2][kr] = v.z;
            tile[nc4 + 3][kr] = v.w;
        }
        __syncthreads();
        {
            int nl = t >> 3, kq = (t & 7) * 4;
            union { _Float16 h[4]; uint2 v; } hi;
#pragma unroll
            for (int j = 0; j < 4; ++j)
                hi.h[j] = (_Float16)tile[nl][kq + j];
            size_t base = (size_t)z * D * D + (size_t)(n0 + nl) * D + k0 + kq;
            *(uint2*)(wT16 + base) = hi.v;
        }
    }
}

// ---------------------------------------------------------------------------
// fp16 MFMA GEMM (R6/R8-proven dbuf structure): C = A@B' + bias.
// B transposed [N][K]; tile 64x64, BK=64, 4 waves; LDS 32 KB double-buffered;
// global_load_lds width16 with pre-swizzled source; slot ^= row&7 swizzle.
// ---------------------------------------------------------------------------
template <typename CT>
__device__ __forceinline__ void gemm_body(
    const _Float16* __restrict__ A, const _Float16* __restrict__ B,
    const float* __restrict__ bias, CT* __restrict__ C,
    int row0, int col0)
{
    __shared__ __align__(16) char lds[2][2][8192];   // [buf][A,B]

    const int t    = threadIdx.x;
    const int lane = t & 63;
    const int w    = t >> 6;
    const int wm   = w >> 1, wn = w & 1;

    const int prow0 = t >> 3;
    const int lslot = (t & 7) ^ (prow0 & 7);

    auto stage = [&](int buf, int k0) {
        size_t a0 = (size_t)(row0 + prow0) * 1024 + k0 * 2 + lslot * 16;
        size_t a1 = a0 + 32 * 1024;
        size_t b0 = (size_t)(col0 + prow0) * 1024 + k0 * 2 + lslot * 16;
        size_t b1 = b0 + 32 * 1024;
        load_lds16((const char*)A + a0, &lds[buf][0][t * 16]);
        load_lds16((const char*)A + a1, &lds[buf][0][4096 + t * 16]);
        load_lds16((const char*)B + b0, &lds[buf][1][t * 16]);
        load_lds16((const char*)B + b1, &lds[buf][1][4096 + t * 16]);
    };

    f32x4 acc[2][2] = {};

    stage(0, 0);
    __syncthreads();

    int cur = 0;
    for (int step = 0; step < 8; ++step) {
        if (step < 7) stage(cur ^ 1, (step + 1) * 64);

        f16x8 fa[2][2], fb[2][2];
#pragma unroll
        for (int mf = 0; mf < 2; ++mf) {
            int row = wm * 32 + mf * 16 + (lane & 15);
#pragma unroll
            for (int ks = 0; ks < 2; ++ks) {
                int ps = ((ks * 4 + (lane >> 4)) ^ (row & 7)) << 4;
                fa[mf][ks] = *(const f16x8*)&lds[cur][0][row * 128 + ps];
            }
        }
#pragma unroll
        for (int nf = 0; nf < 2; ++nf) {
            int row = wn * 32 + nf * 16 + (lane & 15);
#pragma unroll
            for (int ks = 0; ks < 2; ++ks) {
                int ps = ((ks * 4 + (lane >> 4)) ^ (row & 7)) << 4;
                fb[nf][ks] = *(const f16x8*)&lds[cur][1][row * 128 + ps];
            }
        }
#pragma unroll
        for (int mf = 0; mf < 2; ++mf)
#pragma unroll
            for (int nf = 0; nf < 2; ++nf)
#pragma unroll
                for (int ks = 0; ks < 2; ++ks)
                    acc[mf][nf] = __builtin_amdgcn_mfma_f32_16x16x32_f16(
                        fa[mf][ks], fb[nf][ks], acc[mf][nf], 0, 0, 0);

        __syncthreads();
        cur ^= 1;
    }

    // epilogue: C/D layout col=lane&15, row=(lane>>4)*4+reg
#pragma unroll
    for (int mf = 0; mf < 2; ++mf)
#pragma unroll
        for (int nf = 0; nf < 2; ++nf) {
            int col = col0 + wn * 32 + nf * 16 + (lane & 15);
            float bv = bias[col];
#pragma unroll
            for (int r = 0; r < 4; ++r) {
                int row = row0 + wm * 32 + mf * 16 + (lane >> 4) * 4 + r;
                C[(size_t)row * D + col] = (CT)(acc[mf][nf][r] + bv);
            }
        }
}

struct GemmArgs {
    const _Float16 *A, *BT;
    const float* bias[3];
    void* C;
};

__global__ __launch_bounds__(256) void gemm_qkv_kernel(GemmArgs a)
{
    const int z = blockIdx.z;
    gemm_body<_Float16>(a.A, a.BT + (size_t)z * D * D, a.bias[z],
                        (_Float16*)a.C + (size_t)z * (size_t)N_NODES * D,
                        blockIdx.y * 64, blockIdx.x * 64);
}

__global__ __launch_bounds__(256) void gemm_out_kernel(GemmArgs a)
{
    gemm_body<float>(a.A, a.BT, a.bias[0], (float*)a.C,
                     blockIdx.y * 64, blockIdx.x * 64);
}

// ---------------------------------------------------------------------------
// Per-(graph, head) attention with INLINE edge winner scan (deterministic
// exact ".set": LDS atomicMax over edge index) + inline edge-bias dot.
// fp16 QKV in (fp32 LDS tiles), fp16 AO out. 512 blocks x 1024 thr.
// ---------------------------------------------------------------------------
__global__ __launch_bounds__(1024) void attn_kernel(
    const _Float16* __restrict__ QKV16,
    const float* __restrict__ edges, const float* __restrict__ We,
    const float* __restrict__ be,
    const int* __restrict__ snd, const int* __restrict__ rcv,
    _Float16* __restrict__ AO16)
{
    const int g = blockIdx.x;
    const int h = blockIdx.y;
    __shared__ float Qs[32][64];
    __shared__ float Ks[32][65];
    __shared__ float Vs[32][65];
    __shared__ float P[32][33];
    __shared__ int   win[1024];
    __shared__ float WesH[E];

    const int t = threadIdx.x;
    win[t] = -1;
    if (t < E) WesH[t] = We[t * H + h];

    const _Float16* Q16 = QKV16;
    const _Float16* K16 = QKV16 + (size_t)N_NODES * D;
    const _Float16* V16 = QKV16 + (size_t)2 * N_NODES * D;
    for (int idx = t; idx < 32 * 64; idx += 1024) {
        int n = idx >> 6, d = idx & 63;
        size_t ga = (size_t)(g * 32 + n) * D + h * HD + d;
        Qs[n][d] = (float)Q16[ga];
        Ks[n][d] = (float)K16[ga];
        Vs[n][d] = (float)V16[ga];
    }
    __syncthreads();

    // winner scan: 16 iterations over all edges (L2-resident after 1st block)
    for (int it = 0; it < M_EDGES / 1024; ++it) {
        int m = it * 1024 + t;
        int s = snd[m], r = rcv[m];
        if ((s >> 5) == g && (r >> 5) == g)
            atomicMax(&win[((r & 31) << 5) | (s & 31)], m);
    }
    __syncthreads();

    const int i = t >> 5;          // query row (receiver)
    const int j = t & 31;          // key col (sender)
    float s = 0.f;
#pragma unroll
    for (int d = 0; d < 64; ++d) s += Qs[i][d] * Ks[j][d];
    s *= 0.125f;

    int m = win[(i << 5) | j];
    if (m >= 0) {
        float v = be[h];
#pragma unroll
        for (int e = 0; e < E; ++e) v += edges[m * E + e] * WesH[e];
        s += v;
    }

    float mx = s;
#pragma unroll
    for (int o = 16; o > 0; o >>= 1) mx = fmaxf(mx, __shfl_xor(mx, o));
    float p = __expf(s - mx);
    float sum = p;
#pragma unroll
    for (int o = 16; o > 0; o >>= 1) sum += __shfl_xor(sum, o);
    p /= sum;
    P[i][j] = p;
    __syncthreads();

    float o0 = 0.f, o1 = 0.f;
#pragma unroll
    for (int kk = 0; kk < 32; ++kk) {
        float pv = P[i][kk];
        o0 += pv * Vs[kk][j];
        o1 += pv * Vs[kk][j + 32];
    }
    size_t oa = (size_t)(g * 32 + i) * D + h * HD;
    AO16[oa + j]      = (_Float16)o0;
    AO16[oa + j + 32] = (_Float16)o1;
}

// ---------------------------------------------------------------------------
extern "C" void kernel_launch(void* const* d_in, const int* in_sizes, int n_in,
                              void* d_out, int out_size, void* d_ws, size_t ws_size,
                              hipStream_t stream)
{
    const float* nodes = (const float*)d_in[0];
    const float* edges = (const float*)d_in[1];
    const float* Wq    = (const float*)d_in[2];
    const float* bq    = (const float*)d_in[3];
    const float* Wk    = (const float*)d_in[4];
    const float* bk    = (const float*)d_in[5];
    const float* Wv    = (const float*)d_in[6];
    const float* bv    = (const float*)d_in[7];
    const float* Wo    = (const float*)d_in[8];
    const float* bo    = (const float*)d_in[9];
    const float* We    = (const float*)d_in[10];
    const float* be    = (const float*)d_in[11];
    const int* senders   = (const int*)d_in[13];
    const int* receivers = (const int*)d_in[14];

    // workspace layout
    char* ws = (char*)d_ws;
    _Float16* nA16  = (_Float16*)ws;                       // 2 MB
    _Float16* wT16  = nA16 + (size_t)N_NODES * D;          // 2 MB (4x512x512)
    _Float16* QKV16 = wT16 + (size_t)4 * D * D;            // 6 MB (3x2048x512)
    _Float16* AO16  = QKV16 + (size_t)3 * N_NODES * D;     // 2 MB

    // 1) prep: node cast + weight transpose/cast
    prep_kernel<<<1536, 256, 0, stream>>>(nodes, Wq, Wk, Wv, Wo, nA16, wT16);

    // 2) QKV GEMM -> fp16
    GemmArgs qkv;
    qkv.A = nA16;
    qkv.BT = wT16;
    qkv.bias[0] = bq; qkv.bias[1] = bk; qkv.bias[2] = bv;
    qkv.C = QKV16;
    gemm_qkv_kernel<<<dim3(D / 64, N_NODES / 64, 3), 256, 0, stream>>>(qkv);

    // 3) attention (inline winner + edge bias)
    attn_kernel<<<dim3(G, H), 1024, 0, stream>>>(
        QKV16, edges, We, be, senders, receivers, AO16);

    // 4) output GEMM (Wo at slot 3)
    GemmArgs og;
    og.A = AO16;
    og.BT = wT16 + (size_t)3 * D * D;
    og.bias[0] = bo; og.bias[1] = bo; og.bias[2] = bo;
    og.C = d_out;
    gemm_out_kernel<<<dim3(D / 64, N_NODES / 64), 256, 0, stream>>>(og);
}